// Round 14
// baseline (446.806 us; speedup 1.0000x reference)
//
#include <hip/hip_runtime.h>
#include <hip/hip_bf16.h>
#include <math.h>

typedef __attribute__((ext_vector_type(8))) short bf16x8;   // 8 bf16 in 4 VGPRs
typedef __attribute__((ext_vector_type(4))) float f32x4;
typedef __attribute__((ext_vector_type(4))) unsigned short u16x4;

namespace {
constexpr int kB = 2, kS = 2048, kD = 1024, kH = 16, kDK = 64, kDV = 64, kDFF = 4096;
constexpr float kEps = 1e-6f;
constexpr int kM = kB * kS;  // 4096
}

__device__ inline float fast_exp2(float x) {
    return __builtin_amdgcn_exp2f(x);   // v_exp_f32: D = 2^S0
}

__device__ inline unsigned short f2bf(float f) {
    unsigned int u = __builtin_bit_cast(unsigned int, f);
    u += 0x7fffu + ((u >> 16) & 1u);   // round-nearest-even
    return (unsigned short)(u >> 16);
}
__device__ inline float bf2f(unsigned short u) {
    unsigned int x = ((unsigned int)u) << 16;
    return __builtin_bit_cast(float, x);
}

__device__ inline void gload_lds16(const void* g, void* l) {
    __builtin_amdgcn_global_load_lds(
        (const __attribute__((address_space(1))) unsigned int*)g,
        (__attribute__((address_space(3))) unsigned int*)l, 16, 0, 0);
}

// ---------------------------------------------------------------------------
// Merged f32 -> bf16 convert for ALL weights (dst regions are contiguous).
// ---------------------------------------------------------------------------
__global__ __launch_bounds__(256) void cvt_weights(
    const float* __restrict__ s_wqs, const float* __restrict__ s_wks,
    const float* __restrict__ s_wvs, const float* __restrict__ s_fcw,
    const float* __restrict__ s_w1,  const float* __restrict__ s_w2,
    unsigned short* __restrict__ dst)
{
    const int total = 3145728;  // quads
    int i = blockIdx.x * 256 + threadIdx.x;
    const int stride = gridDim.x * 256;
    for (; i < total; i += stride) {
        const float* src; int off;
        if      (i <  262144) { src = s_wqs; off = i; }
        else if (i <  524288) { src = s_wks; off = i -  262144; }
        else if (i <  786432) { src = s_wvs; off = i -  524288; }
        else if (i < 1048576) { src = s_fcw; off = i -  786432; }
        else if (i < 2097152) { src = s_w1;  off = i - 1048576; }
        else                  { src = s_w2;  off = i - 2097152; }
        const float4 v = ((const float4*)src)[off];
        u16x4 o;
        o.x = f2bf(v.x); o.y = f2bf(v.y); o.z = f2bf(v.z); o.w = f2bf(v.w);
        ((u16x4*)dst)[i] = o;
    }
}

// ---------------------------------------------------------------------------
// LayerNorm, optionally also emitting the raw input as bf16.
// ---------------------------------------------------------------------------
template<bool DUAL>
__global__ __launch_bounds__(256) void ln_bf16_kernel(
    const float* __restrict__ x, const float* __restrict__ g,
    const float* __restrict__ b, unsigned short* __restrict__ out,
    unsigned short* __restrict__ out_raw)
{
    const size_t row = blockIdx.x;
    const float4 v = ((const float4*)(x + row * kD))[threadIdx.x];
    if (DUAL) {
        u16x4 r;
        r.x = f2bf(v.x); r.y = f2bf(v.y); r.z = f2bf(v.z); r.w = f2bf(v.w);
        ((u16x4*)(out_raw + row * kD))[threadIdx.x] = r;
    }
    float s = v.x + v.y + v.z + v.w;
    float q = v.x * v.x + v.y * v.y + v.z * v.z + v.w * v.w;
#pragma unroll
    for (int off = 32; off > 0; off >>= 1) {
        s += __shfl_down(s, off);
        q += __shfl_down(q, off);
    }
    __shared__ float rs[4], rq[4];
    const int wid = threadIdx.x >> 6, lane = threadIdx.x & 63;
    if (lane == 0) { rs[wid] = s; rq[wid] = q; }
    __syncthreads();
    const float ts = rs[0] + rs[1] + rs[2] + rs[3];
    const float tq = rq[0] + rq[1] + rq[2] + rq[3];
    const float mean = ts * (1.0f / kD);
    const float var  = tq * (1.0f / kD) - mean * mean;
    const float rstd = rsqrtf(var + kEps);
    const float4 gg = ((const float4*)g)[threadIdx.x];
    const float4 bb = ((const float4*)b)[threadIdx.x];
    u16x4 o;
    o.x = f2bf((v.x - mean) * rstd * gg.x + bb.x);
    o.y = f2bf((v.y - mean) * rstd * gg.y + bb.y);
    o.z = f2bf((v.z - mean) * rstd * gg.z + bb.z);
    o.w = f2bf((v.w - mean) * rstd * gg.w + bb.w);
    ((u16x4*)(out + row * kD))[threadIdx.x] = o;
}

// ---------------------------------------------------------------------------
// Fused Q/K/V projection: 128x128 tiles, 768 blocks = 3/CU.
// ---------------------------------------------------------------------------
__global__ __launch_bounds__(256) void qkv_gemm(
    const unsigned short* __restrict__ qinb,
    const unsigned short* __restrict__ xb,
    const unsigned short* __restrict__ wq,
    const unsigned short* __restrict__ wk,
    const unsigned short* __restrict__ wv,
    unsigned short* __restrict__ Qb,
    unsigned short* __restrict__ Kb,
    unsigned short* __restrict__ Vt)
{
    __shared__ __align__(16) unsigned short As[128 * 32];
    __shared__ __align__(16) unsigned short Bs[128 * 32];

    const int m0  = blockIdx.y * 128;
    const int n0g = blockIdx.x * 128;
    const int which = n0g >> 10;          // 0=Q, 1=K, 2=V
    const int n0  = n0g & 1023;
    const unsigned short* A = (which == 0) ? qinb : xb;
    const unsigned short* B = (which == 0) ? wq : (which == 1 ? wk : wv);

    const int t = threadIdx.x;
    const int w = t >> 6, lane = t & 63;
    const int wm = (w >> 1) * 64;
    const int wn = (w & 1) * 64;

    f32x4 acc[4][4];
#pragma unroll
    for (int m = 0; m < 4; ++m)
#pragma unroll
        for (int n = 0; n < 4; ++n) acc[m][n] = (f32x4){0.f, 0.f, 0.f, 0.f};

    for (int k0 = 0; k0 < kD; k0 += 32) {
#pragma unroll
        for (int i = 0; i < 2; ++i) {
            const int r = i * 64 + (t >> 2);
            gload_lds16(A + (size_t)(m0 + r) * kD + k0 + (t & 3) * 8,
                        As + r * 32 + (t & 3) * 8);
            gload_lds16(B + (size_t)(n0 + r) * kD + k0 + (t & 3) * 8,
                        Bs + r * 32 + (t & 3) * 8);
        }
        __syncthreads();

        bf16x8 a[4], bb[4];
#pragma unroll
        for (int m = 0; m < 4; ++m)
            a[m] = *(const bf16x8*)(As + (wm + m * 16 + (lane & 15)) * 32 + (lane >> 4) * 8);
#pragma unroll
        for (int n = 0; n < 4; ++n)
            bb[n] = *(const bf16x8*)(Bs + (wn + n * 16 + (lane & 15)) * 32 + (lane >> 4) * 8);
#pragma unroll
        for (int m = 0; m < 4; ++m)
#pragma unroll
            for (int n = 0; n < 4; ++n)
                acc[m][n] = __builtin_amdgcn_mfma_f32_16x16x32_bf16(a[m], bb[n], acc[m][n], 0, 0, 0);
        __syncthreads();
    }

    const int col = lane & 15, rb = (lane >> 4) * 4;
#pragma unroll
    for (int m = 0; m < 4; ++m)
#pragma unroll
        for (int n = 0; n < 4; ++n)
#pragma unroll
            for (int j = 0; j < 4; ++j) {
                const int gm  = m0 + wm + m * 16 + rb + j;
                const int gnl = n0 + wn + n * 16 + col;
                const unsigned short bv = f2bf(acc[m][n][j]);
                if (which == 0)
                    Qb[(size_t)gm * kD + gnl] = bv;
                else if (which == 1)
                    Kb[(size_t)gm * kD + gnl] = bv;
                else
                    Vt[((size_t)(gm >> 11) * kD + gnl) * kS + (gm & 2047)] = bv;
            }
}

// ---------------------------------------------------------------------------
// bf16 MFMA GEMM (m97 structure), BM/BN-parameterized.
// BM=64 halves LDS (12 KB) and acc state -> ~2x resident blocks/CU (the R13
// occupancy lever applied to GEMM). Used with BM=64 for fc and FFN2
// (grid (8,64) = 512 blocks), BM=128 for FFN1 (grid (32,32) = 1024 blocks).
// ---------------------------------------------------------------------------
template<int BM, int BN, bool OUTB, bool BIAS, bool RES, bool GELU>
__global__ __launch_bounds__(256) void gemm_mfma(
    const unsigned short* __restrict__ A, int lda,
    const unsigned short* __restrict__ B, int ldb,
    void* __restrict__ Cbase, int ldc,
    const float* __restrict__ bias,
    const float* __restrict__ resbase, int ldres,
    int K)
{
    __shared__ __align__(16) unsigned short As[BM * 32];
    __shared__ __align__(16) unsigned short Bs[BN * 32];

    float* Cf = (float*)Cbase;
    unsigned short* Cu = (unsigned short*)Cbase;

    const int m0 = blockIdx.y * BM;
    const int n0 = blockIdx.x * BN;
    const int t = threadIdx.x;
    const int w = t >> 6, lane = t & 63;
    const int wm = (w >> 1) * (BM / 2);
    const int wn = (w & 1) * (BN / 2);
    constexpr int AM = (BM / 2) / 16;     // m-frags per wave (4 or 2)
    constexpr int AN = (BN / 2) / 16;     // n-frags per wave (4 or 2)

    f32x4 acc[AM][AN];
#pragma unroll
    for (int m = 0; m < AM; ++m)
#pragma unroll
        for (int n = 0; n < AN; ++n) acc[m][n] = (f32x4){0.f, 0.f, 0.f, 0.f};

    for (int k0 = 0; k0 < K; k0 += 32) {
#pragma unroll
        for (int i = 0; i < BM / 64; ++i) {
            const int r = i * 64 + (t >> 2);
            gload_lds16(A + (size_t)(m0 + r) * lda + k0 + (t & 3) * 8,
                        As + r * 32 + (t & 3) * 8);
        }
#pragma unroll
        for (int i = 0; i < BN / 64; ++i) {
            const int r = i * 64 + (t >> 2);
            gload_lds16(B + (size_t)(n0 + r) * ldb + k0 + (t & 3) * 8,
                        Bs + r * 32 + (t & 3) * 8);
        }
        __syncthreads();

        bf16x8 a[AM], bb[AN];
#pragma unroll
        for (int m = 0; m < AM; ++m)
            a[m] = *(const bf16x8*)(As + (wm + m * 16 + (lane & 15)) * 32 + (lane >> 4) * 8);
#pragma unroll
        for (int n = 0; n < AN; ++n)
            bb[n] = *(const bf16x8*)(Bs + (wn + n * 16 + (lane & 15)) * 32 + (lane >> 4) * 8);
#pragma unroll
        for (int m = 0; m < AM; ++m)
#pragma unroll
            for (int n = 0; n < AN; ++n)
                acc[m][n] = __builtin_amdgcn_mfma_f32_16x16x32_bf16(a[m], bb[n], acc[m][n], 0, 0, 0);
        __syncthreads();
    }

    const int col = lane & 15, rb = (lane >> 4) * 4;
#pragma unroll
    for (int m = 0; m < AM; ++m)
#pragma unroll
        for (int n = 0; n < AN; ++n)
#pragma unroll
            for (int j = 0; j < 4; ++j) {
                const int gm = m0 + wm + m * 16 + rb + j;
                const int gn = n0 + wn + n * 16 + col;
                float v = acc[m][n][j];
                if (BIAS) v += bias[gn];
                if (GELU) v = 0.5f * v * (1.0f + erff(v * 0.7071067811865476f));
                if (RES)  v += resbase[(size_t)gm * ldres + gn];
                if (OUTB) Cu[(size_t)gm * ldc + gn] = f2bf(v);
                else      Cf[(size_t)gm * ldc + gn] = v;
            }
}

// ---------------------------------------------------------------------------
// Fused attention v4 (R13, unchanged): QBLK=64, grid 1024 = 4 blocks/CU.
// No-max softmax via exp2. Plain __syncthreads.
// ---------------------------------------------------------------------------
__global__ __launch_bounds__(256) void fused_attn(
    const unsigned short* __restrict__ Qb,
    const unsigned short* __restrict__ Kb,
    const unsigned short* __restrict__ Vt,
    float* __restrict__ attn,
    unsigned short* __restrict__ ctx)
{
    __shared__ __align__(16) unsigned short KVs[128][72];  // p1: K128 | p2: K64+V64
    __shared__ __align__(16) unsigned short Ps[64][72];

    const int z = blockIdx.y, b = z >> 4, h = z & 15;
    const int qt = blockIdx.x;                 // 32 tiles of 64 q-rows
    const int t = threadIdx.x, w = t >> 6, lane = t & 63;
    const int l16 = lane & 15, lhi = lane >> 4;

    const unsigned short* Qp = Qb + (size_t)b * kS * kD + (size_t)h * kDK;
    const unsigned short* Kp = Kb + (size_t)b * kS * kD + (size_t)h * kDK;
    const unsigned short* Vp = Vt + (size_t)(b * kD + h * kDV) * kS;
    float* Ap = attn + (size_t)z * kS * kS;

    // ---- Q fragments in registers, pre-scaled by 0.125*log2(e) ----
    bf16x8 q[2];
    const int qrow0 = qt * 64 + w * 16;
#pragma unroll
    for (int kq = 0; kq < 2; ++kq) {
        bf16x8 v = *(const bf16x8*)(Qp + (size_t)(qrow0 + l16) * kD + kq * 32 + lhi * 8);
#pragma unroll
        for (int e = 0; e < 8; ++e)
            v[e] = (short)f2bf(bf2f((unsigned short)v[e]) * 0.18033688011112042f);
        q[kq] = v;
    }

    float lrow[4] = {0.f, 0.f, 0.f, 0.f};

    // ====== pass 1: row sums, 128 keys per LDS stage (16 iters) ======
    for (int kt = 0; kt < 16; ++kt) {
#pragma unroll
        for (int i = 0; i < 4; ++i) {
            const int r = i * 32 + (t >> 3), c = (t & 7) * 8;
            *(bf16x8*)&KVs[r][c] = *(const bf16x8*)(Kp + (size_t)(kt * 128 + r) * kD + c);
        }
        __syncthreads();

        f32x4 s[8];
#pragma unroll
        for (int n = 0; n < 8; ++n) s[n] = (f32x4){0.f, 0.f, 0.f, 0.f};
#pragma unroll
        for (int kq = 0; kq < 2; ++kq)
#pragma unroll
            for (int n = 0; n < 8; ++n) {
                const bf16x8 kf = *(const bf16x8*)&KVs[n * 16 + l16][kq * 32 + lhi * 8];
                s[n] = __builtin_amdgcn_mfma_f32_16x16x32_bf16(q[kq], kf, s[n], 0, 0, 0);
            }

#pragma unroll
        for (int j = 0; j < 4; ++j) {
            float sum = ((fast_exp2(s[0][j]) + fast_exp2(s[1][j]))
                       + (fast_exp2(s[2][j]) + fast_exp2(s[3][j])))
                      + ((fast_exp2(s[4][j]) + fast_exp2(s[5][j]))
                       + (fast_exp2(s[6][j]) + fast_exp2(s[7][j])));
#pragma unroll
            for (int off = 1; off < 16; off <<= 1) sum += __shfl_xor(sum, off);
            lrow[j] += sum;
        }
        __syncthreads();
    }

    float invl[4];
#pragma unroll
    for (int j = 0; j < 4; ++j) invl[j] = 1.0f / lrow[j];

    // ====== pass 2: P = exp2(s)/l, write attn, O += P*V (KVBLK=64) ======
    f32x4 o[4];
#pragma unroll
    for (int n = 0; n < 4; ++n) o[n] = (f32x4){0.f, 0.f, 0.f, 0.f};

    for (int kt = 0; kt < 32; ++kt) {
#pragma unroll
        for (int i = 0; i < 2; ++i) {
            const int r = i * 32 + (t >> 3), c = (t & 7) * 8;
            *(bf16x8*)&KVs[r][c]      = *(const bf16x8*)(Kp + (size_t)(kt * 64 + r) * kD + c);
            *(bf16x8*)&KVs[64 + r][c] = *(const bf16x8*)(Vp + (size_t)r * kS + kt * 64 + c);
        }
        __syncthreads();

        f32x4 s[4];
#pragma unroll
        for (int n = 0; n < 4; ++n) s[n] = (f32x4){0.f, 0.f, 0.f, 0.f};
#pragma unroll
        for (int kq = 0; kq < 2; ++kq)
#pragma unroll
            for (int n = 0; n < 4; ++n) {
                const bf16x8 kf = *(const bf16x8*)&KVs[n * 16 + l16][kq * 32 + lhi * 8];
                s[n] = __builtin_amdgcn_mfma_f32_16x16x32_bf16(q[kq], kf, s[n], 0, 0, 0);
            }

        // P = exp2(s) * invl -> Ps (bf16)
#pragma unroll
        for (int j = 0; j < 4; ++j) {
            const int qrow_l = w * 16 + lhi * 4 + j;
#pragma unroll
            for (int n = 0; n < 4; ++n) {
                const float p = fast_exp2(s[n][j]) * invl[j];
                Ps[qrow_l][n * 16 + l16] = f2bf(p);
            }
        }
        __syncthreads();   // Ps visible before PV reads + attn writeback

        // attn writeback: contiguous nontemporal f32x4 streams (64 rows)
#pragma unroll
        for (int rg = 0; rg < 2; ++rg) {
            const int row = rg * 32 + (t >> 3);
            const int cb  = (t & 7) * 8;
            const bf16x8 pv = *(const bf16x8*)&Ps[row][cb];
            f32x4 f0, f1;
            f0.x = bf2f((unsigned short)pv[0]); f0.y = bf2f((unsigned short)pv[1]);
            f0.z = bf2f((unsigned short)pv[2]); f0.w = bf2f((unsigned short)pv[3]);
            f1.x = bf2f((unsigned short)pv[4]); f1.y = bf2f((unsigned short)pv[5]);
            f1.z = bf2f((unsigned short)pv[6]); f1.w = bf2f((unsigned short)pv[7]);
            float* dst = Ap + (size_t)(qt * 64 + row) * kS + kt * 64 + cb;
            __builtin_nontemporal_store(f0, (f32x4*)dst);
            __builtin_nontemporal_store(f1, (f32x4*)(dst + 4));
        }

#pragma unroll
        for (int ks = 0; ks < 2; ++ks) {
            const bf16x8 pa = *(const bf16x8*)&Ps[w * 16 + l16][ks * 32 + lhi * 8];
#pragma unroll
            for (int n = 0; n < 4; ++n) {
                const bf16x8 vf = *(const bf16x8*)&KVs[64 + n * 16 + l16][ks * 32 + lhi * 8];
                o[n] = __builtin_amdgcn_mfma_f32_16x16x32_bf16(pa, vf, o[n], 0, 0, 0);
            }
        }
        __syncthreads();   // all reads done before next tile overwrites
    }

    // ---- ctx write: [B,S,H*DV] bf16 ----
#pragma unroll
    for (int n = 0; n < 4; ++n)
#pragma unroll
        for (int j = 0; j < 4; ++j) {
            const int qg = qt * 64 + w * 16 + lhi * 4 + j;
            const int dv = n * 16 + l16;
            ctx[((size_t)b * kS + qg) * kD + h * kDV + dv] = f2bf(o[n][j]);
        }
}

// ---------------------------------------------------------------------------
extern "C" void kernel_launch(void* const* d_in, const int* in_sizes, int n_in,
                              void* d_out, int out_size, void* d_ws, size_t ws_size,
                              hipStream_t stream) {
    (void)in_sizes; (void)n_in; (void)out_size; (void)ws_size;

    const float* x      = (const float*)d_in[0];
    const float* w_qs   = (const float*)d_in[1];
    const float* w_ks   = (const float*)d_in[2];
    const float* w_vs   = (const float*)d_in[3];
    const float* fc_w   = (const float*)d_in[4];
    const float* fc_b   = (const float*)d_in[5];
    const float* ln1_g  = (const float*)d_in[6];
    const float* ln1_b  = (const float*)d_in[7];
    const float* ffn_w1 = (const float*)d_in[8];
    const float* ffn_b1 = (const float*)d_in[9];
    const float* ffn_w2 = (const float*)d_in[10];
    const float* ffn_b2 = (const float*)d_in[11];
    const float* ln2_g  = (const float*)d_in[12];
    const float* ln2_b  = (const float*)d_in[13];

    float* out_enc  = (float*)d_out;                   // [B,S,D] f32
    float* out_attn = out_enc + (size_t)kM * kD;       // [B,H,S,S] f32

    // Workspace (128 MB)
    unsigned short* xb   = (unsigned short*)d_ws;      // x bf16
    unsigned short* qinb = xb   + (size_t)4194304;     // LN1(x)
    unsigned short* Qb   = qinb + (size_t)4194304;     // Q
    unsigned short* Kb   = Qb   + (size_t)4194304;     // K
    unsigned short* Vt   = Kb   + (size_t)4194304;     // V^T
    unsigned short* ctxb = Vt   + (size_t)4194304;     // ctx
    unsigned short* hb   = ctxb + (size_t)4194304;     // LN2(attn_out)
    unsigned short* gb   = hb   + (size_t)4194304;     // gelu out
    unsigned short* wqsb = gb   + (size_t)16777216;    // weights bf16 (contig 12M)
    unsigned short* wksb = wqsb + (size_t)1048576;
    unsigned short* wvsb = wksb + (size_t)1048576;
    unsigned short* fcwb = wvsb + (size_t)1048576;
    unsigned short* w1b  = fcwb + (size_t)1048576;
    unsigned short* w2b  = w1b  + (size_t)4194304;
    float* attn_out      = (float*)(w2b + (size_t)4194304);  // f32 16MB

    const dim3 blk(256);

    // ---- all weight converts in one dispatch ----
    cvt_weights<<<2048, blk, 0, stream>>>(w_qs, w_ks, w_vs, fc_w, ffn_w1, ffn_w2, wqsb);

    // ---- LN1 (also emits x as bf16) ----
    ln_bf16_kernel<true><<<kM, blk, 0, stream>>>(x, ln1_g, ln1_b, qinb, xb);

    // ---- fused Q/K/V projections ----
    qkv_gemm<<<dim3(24, 32), blk, 0, stream>>>(qinb, xb, wqsb, wksb, wvsb, Qb, Kb, Vt);

    // ---- fused scores+softmax+PV (QBLK=64, 1024 blocks = 4/CU) ----
    fused_attn<<<dim3(32, 32), blk, 0, stream>>>(Qb, Kb, Vt, out_attn, ctxb);

    // ---- attn_out = ctx @ fc_w^T + fc_b + x (f32): BM=64, 512 blocks ----
    gemm_mfma<64, 128, false, true, true, false><<<dim3(8, 64), blk, 0, stream>>>(
        ctxb, kD, fcwb, kD, attn_out, kD, fc_b, x, kD, kD);

    // ---- LN2 ----
    ln_bf16_kernel<false><<<kM, blk, 0, stream>>>(attn_out, ln2_g, ln2_b, hb, nullptr);

    // ---- g = gelu(h @ ffn_w1^T + b1) -> bf16 (128^2, 1024 blocks) ----
    gemm_mfma<128, 128, true, true, false, true><<<dim3(32, 32), blk, 0, stream>>>(
        hb, kD, w1b, kD, gb, kDFF, ffn_b1, nullptr, 0, kD);

    // ---- enc_out = g @ ffn_w2^T + b2 + attn_out (f32): BM=64, 512 blocks ----
    gemm_mfma<64, 128, false, true, true, false><<<dim3(8, 64), blk, 0, stream>>>(
        gb, kDFF, w2b, kDFF, out_enc, kD, ffn_b2, attn_out, kD, kDFF);
}

// Round 15
// 441.407 us; speedup vs baseline: 1.0122x; 1.0122x over previous
//
#include <hip/hip_runtime.h>
#include <hip/hip_bf16.h>
#include <math.h>

typedef __attribute__((ext_vector_type(8))) short bf16x8;   // 8 bf16 in 4 VGPRs
typedef __attribute__((ext_vector_type(4))) float f32x4;
typedef __attribute__((ext_vector_type(4))) unsigned short u16x4;

namespace {
constexpr int kB = 2, kS = 2048, kD = 1024, kH = 16, kDK = 64, kDV = 64, kDFF = 4096;
constexpr float kEps = 1e-6f;
constexpr int kM = kB * kS;  // 4096
}

__device__ inline float fast_exp2(float x) {
    return __builtin_amdgcn_exp2f(x);   // v_exp_f32: D = 2^S0
}

__device__ inline unsigned short f2bf(float f) {
    unsigned int u = __builtin_bit_cast(unsigned int, f);
    u += 0x7fffu + ((u >> 16) & 1u);   // round-nearest-even
    return (unsigned short)(u >> 16);
}
__device__ inline float bf2f(unsigned short u) {
    unsigned int x = ((unsigned int)u) << 16;
    return __builtin_bit_cast(float, x);
}

__device__ inline void gload_lds16(const void* g, void* l) {
    __builtin_amdgcn_global_load_lds(
        (const __attribute__((address_space(1))) unsigned int*)g,
        (__attribute__((address_space(3))) unsigned int*)l, 16, 0, 0);
}

// ---------------------------------------------------------------------------
// Merged f32 -> bf16 convert for ALL weights (dst regions are contiguous).
// ---------------------------------------------------------------------------
__global__ __launch_bounds__(256) void cvt_weights(
    const float* __restrict__ s_wqs, const float* __restrict__ s_wks,
    const float* __restrict__ s_wvs, const float* __restrict__ s_fcw,
    const float* __restrict__ s_w1,  const float* __restrict__ s_w2,
    unsigned short* __restrict__ dst)
{
    const int total = 3145728;  // quads
    int i = blockIdx.x * 256 + threadIdx.x;
    const int stride = gridDim.x * 256;
    for (; i < total; i += stride) {
        const float* src; int off;
        if      (i <  262144) { src = s_wqs; off = i; }
        else if (i <  524288) { src = s_wks; off = i -  262144; }
        else if (i <  786432) { src = s_wvs; off = i -  524288; }
        else if (i < 1048576) { src = s_fcw; off = i -  786432; }
        else if (i < 2097152) { src = s_w1;  off = i - 1048576; }
        else                  { src = s_w2;  off = i - 2097152; }
        const float4 v = ((const float4*)src)[off];
        u16x4 o;
        o.x = f2bf(v.x); o.y = f2bf(v.y); o.z = f2bf(v.z); o.w = f2bf(v.w);
        ((u16x4*)dst)[i] = o;
    }
}

// ---------------------------------------------------------------------------
// LayerNorm, wave-per-row: 4 rows/block, no LDS, no barriers (pure 6-step
// shuffle reduce). 16 f32/lane over D=1024. Optionally emits raw bf16 too.
// ---------------------------------------------------------------------------
template<bool DUAL>
__global__ __launch_bounds__(256) void ln_bf16_kernel(
    const float* __restrict__ x, const float* __restrict__ g,
    const float* __restrict__ b, unsigned short* __restrict__ out,
    unsigned short* __restrict__ out_raw)
{
    const int wid = threadIdx.x >> 6, lane = threadIdx.x & 63;
    const size_t row = blockIdx.x * 4 + wid;
    const float4* xr = (const float4*)(x + row * kD);

    float4 v[4];
    float s = 0.f, q = 0.f;
#pragma unroll
    for (int i = 0; i < 4; ++i) {
        v[i] = xr[lane + 64 * i];
        s += v[i].x + v[i].y + v[i].z + v[i].w;
        q += v[i].x * v[i].x + v[i].y * v[i].y + v[i].z * v[i].z + v[i].w * v[i].w;
    }
    if (DUAL) {
#pragma unroll
        for (int i = 0; i < 4; ++i) {
            u16x4 r;
            r.x = f2bf(v[i].x); r.y = f2bf(v[i].y);
            r.z = f2bf(v[i].z); r.w = f2bf(v[i].w);
            ((u16x4*)(out_raw + row * kD))[lane + 64 * i] = r;
        }
    }
#pragma unroll
    for (int off = 32; off > 0; off >>= 1) {
        s += __shfl_xor(s, off);
        q += __shfl_xor(q, off);
    }
    const float mean = s * (1.0f / kD);
    const float var  = q * (1.0f / kD) - mean * mean;
    const float rstd = rsqrtf(var + kEps);
#pragma unroll
    for (int i = 0; i < 4; ++i) {
        const float4 gg = ((const float4*)g)[lane + 64 * i];
        const float4 bb = ((const float4*)b)[lane + 64 * i];
        u16x4 o;
        o.x = f2bf((v[i].x - mean) * rstd * gg.x + bb.x);
        o.y = f2bf((v[i].y - mean) * rstd * gg.y + bb.y);
        o.z = f2bf((v[i].z - mean) * rstd * gg.z + bb.z);
        o.w = f2bf((v[i].w - mean) * rstd * gg.w + bb.w);
        ((u16x4*)(out + row * kD))[lane + 64 * i] = o;
    }
}

// ---------------------------------------------------------------------------
// Fused Q/K/V projection: 128x128 tiles, 768 blocks = 3/CU.
// ---------------------------------------------------------------------------
__global__ __launch_bounds__(256) void qkv_gemm(
    const unsigned short* __restrict__ qinb,
    const unsigned short* __restrict__ xb,
    const unsigned short* __restrict__ wq,
    const unsigned short* __restrict__ wk,
    const unsigned short* __restrict__ wv,
    unsigned short* __restrict__ Qb,
    unsigned short* __restrict__ Kb,
    unsigned short* __restrict__ Vt)
{
    __shared__ __align__(16) unsigned short As[128 * 32];
    __shared__ __align__(16) unsigned short Bs[128 * 32];

    const int m0  = blockIdx.y * 128;
    const int n0g = blockIdx.x * 128;
    const int which = n0g >> 10;          // 0=Q, 1=K, 2=V
    const int n0  = n0g & 1023;
    const unsigned short* A = (which == 0) ? qinb : xb;
    const unsigned short* B = (which == 0) ? wq : (which == 1 ? wk : wv);

    const int t = threadIdx.x;
    const int w = t >> 6, lane = t & 63;
    const int wm = (w >> 1) * 64;
    const int wn = (w & 1) * 64;

    f32x4 acc[4][4];
#pragma unroll
    for (int m = 0; m < 4; ++m)
#pragma unroll
        for (int n = 0; n < 4; ++n) acc[m][n] = (f32x4){0.f, 0.f, 0.f, 0.f};

    for (int k0 = 0; k0 < kD; k0 += 32) {
#pragma unroll
        for (int i = 0; i < 2; ++i) {
            const int r = i * 64 + (t >> 2);
            gload_lds16(A + (size_t)(m0 + r) * kD + k0 + (t & 3) * 8,
                        As + r * 32 + (t & 3) * 8);
            gload_lds16(B + (size_t)(n0 + r) * kD + k0 + (t & 3) * 8,
                        Bs + r * 32 + (t & 3) * 8);
        }
        __syncthreads();

        bf16x8 a[4], bb[4];
#pragma unroll
        for (int m = 0; m < 4; ++m)
            a[m] = *(const bf16x8*)(As + (wm + m * 16 + (lane & 15)) * 32 + (lane >> 4) * 8);
#pragma unroll
        for (int n = 0; n < 4; ++n)
            bb[n] = *(const bf16x8*)(Bs + (wn + n * 16 + (lane & 15)) * 32 + (lane >> 4) * 8);
#pragma unroll
        for (int m = 0; m < 4; ++m)
#pragma unroll
            for (int n = 0; n < 4; ++n)
                acc[m][n] = __builtin_amdgcn_mfma_f32_16x16x32_bf16(a[m], bb[n], acc[m][n], 0, 0, 0);
        __syncthreads();
    }

    const int col = lane & 15, rb = (lane >> 4) * 4;
#pragma unroll
    for (int m = 0; m < 4; ++m)
#pragma unroll
        for (int n = 0; n < 4; ++n)
#pragma unroll
            for (int j = 0; j < 4; ++j) {
                const int gm  = m0 + wm + m * 16 + rb + j;
                const int gnl = n0 + wn + n * 16 + col;
                const unsigned short bv = f2bf(acc[m][n][j]);
                if (which == 0)
                    Qb[(size_t)gm * kD + gnl] = bv;
                else if (which == 1)
                    Kb[(size_t)gm * kD + gnl] = bv;
                else
                    Vt[((size_t)(gm >> 11) * kD + gnl) * kS + (gm & 2047)] = bv;
            }
}

// ---------------------------------------------------------------------------
// bf16 MFMA GEMM (m97 structure), BM/BN-parameterized.
// R13-proven configs: fc BM=128/BN=64 grid(16,32); FFN1 BM=128/BN=128
// grid(32,32). (R14 showed BM=64 is neutral-to-worse: per-block MFMA:barrier
// ratio halves, cancelling the occupancy gain — m92 tile-size cliff.)
// ---------------------------------------------------------------------------
template<int BM, int BN, bool OUTB, bool BIAS, bool RES, bool GELU>
__global__ __launch_bounds__(256) void gemm_mfma(
    const unsigned short* __restrict__ A, int lda,
    const unsigned short* __restrict__ B, int ldb,
    void* __restrict__ Cbase, int ldc,
    const float* __restrict__ bias,
    const float* __restrict__ resbase, int ldres,
    int K)
{
    __shared__ __align__(16) unsigned short As[BM * 32];
    __shared__ __align__(16) unsigned short Bs[BN * 32];

    float* Cf = (float*)Cbase;
    unsigned short* Cu = (unsigned short*)Cbase;

    const int m0 = blockIdx.y * BM;
    const int n0 = blockIdx.x * BN;
    const int t = threadIdx.x;
    const int w = t >> 6, lane = t & 63;
    const int wm = (w >> 1) * (BM / 2);
    const int wn = (w & 1) * (BN / 2);
    constexpr int AM = (BM / 2) / 16;
    constexpr int AN = (BN / 2) / 16;

    f32x4 acc[AM][AN];
#pragma unroll
    for (int m = 0; m < AM; ++m)
#pragma unroll
        for (int n = 0; n < AN; ++n) acc[m][n] = (f32x4){0.f, 0.f, 0.f, 0.f};

    for (int k0 = 0; k0 < K; k0 += 32) {
#pragma unroll
        for (int i = 0; i < BM / 64; ++i) {
            const int r = i * 64 + (t >> 2);
            gload_lds16(A + (size_t)(m0 + r) * lda + k0 + (t & 3) * 8,
                        As + r * 32 + (t & 3) * 8);
        }
#pragma unroll
        for (int i = 0; i < BN / 64; ++i) {
            const int r = i * 64 + (t >> 2);
            gload_lds16(B + (size_t)(n0 + r) * ldb + k0 + (t & 3) * 8,
                        Bs + r * 32 + (t & 3) * 8);
        }
        __syncthreads();

        bf16x8 a[AM], bb[AN];
#pragma unroll
        for (int m = 0; m < AM; ++m)
            a[m] = *(const bf16x8*)(As + (wm + m * 16 + (lane & 15)) * 32 + (lane >> 4) * 8);
#pragma unroll
        for (int n = 0; n < AN; ++n)
            bb[n] = *(const bf16x8*)(Bs + (wn + n * 16 + (lane & 15)) * 32 + (lane >> 4) * 8);
#pragma unroll
        for (int m = 0; m < AM; ++m)
#pragma unroll
            for (int n = 0; n < AN; ++n)
                acc[m][n] = __builtin_amdgcn_mfma_f32_16x16x32_bf16(a[m], bb[n], acc[m][n], 0, 0, 0);
        __syncthreads();
    }

    const int col = lane & 15, rb = (lane >> 4) * 4;
#pragma unroll
    for (int m = 0; m < AM; ++m)
#pragma unroll
        for (int n = 0; n < AN; ++n)
#pragma unroll
            for (int j = 0; j < 4; ++j) {
                const int gm = m0 + wm + m * 16 + rb + j;
                const int gn = n0 + wn + n * 16 + col;
                float v = acc[m][n][j];
                if (BIAS) v += bias[gn];
                if (GELU) v = 0.5f * v * (1.0f + erff(v * 0.7071067811865476f));
                if (RES)  v += resbase[(size_t)gm * ldres + gn];
                if (OUTB) Cu[(size_t)gm * ldc + gn] = f2bf(v);
                else      Cf[(size_t)gm * ldc + gn] = v;
            }
}

// ---------------------------------------------------------------------------
// Split-K GEMM for FFN2 (R13-proven): 128x128 tiles, grid (8, 32, 2).
// ---------------------------------------------------------------------------
__global__ __launch_bounds__(256) void gemm_splitk(
    const unsigned short* __restrict__ A, int lda,
    const unsigned short* __restrict__ B, int ldb,
    float* __restrict__ P,     // [SPLIT][M][N] f32 partials
    int ldc, int K, int split)
{
    __shared__ __align__(16) unsigned short As[128 * 32];
    __shared__ __align__(16) unsigned short Bs[128 * 32];

    const int m0 = blockIdx.y * 128;
    const int n0 = blockIdx.x * 128;
    const int kz = blockIdx.z;
    const int Kc = K / split;
    const int kbase = kz * Kc;
    float* Pz = P + (size_t)kz * kM * ldc;

    const int t = threadIdx.x;
    const int w = t >> 6, lane = t & 63;
    const int wm = (w >> 1) * 64;
    const int wn = (w & 1) * 64;

    f32x4 acc[4][4];
#pragma unroll
    for (int m = 0; m < 4; ++m)
#pragma unroll
        for (int n = 0; n < 4; ++n) acc[m][n] = (f32x4){0.f, 0.f, 0.f, 0.f};

    for (int k0 = kbase; k0 < kbase + Kc; k0 += 32) {
#pragma unroll
        for (int i = 0; i < 2; ++i) {
            const int r = i * 64 + (t >> 2);
            gload_lds16(A + (size_t)(m0 + r) * lda + k0 + (t & 3) * 8,
                        As + r * 32 + (t & 3) * 8);
            gload_lds16(B + (size_t)(n0 + r) * ldb + k0 + (t & 3) * 8,
                        Bs + r * 32 + (t & 3) * 8);
        }
        __syncthreads();

        bf16x8 a[4], bb[4];
#pragma unroll
        for (int m = 0; m < 4; ++m)
            a[m] = *(const bf16x8*)(As + (wm + m * 16 + (lane & 15)) * 32 + (lane >> 4) * 8);
#pragma unroll
        for (int n = 0; n < 4; ++n)
            bb[n] = *(const bf16x8*)(Bs + (wn + n * 16 + (lane & 15)) * 32 + (lane >> 4) * 8);
#pragma unroll
        for (int m = 0; m < 4; ++m)
#pragma unroll
            for (int n = 0; n < 4; ++n)
                acc[m][n] = __builtin_amdgcn_mfma_f32_16x16x32_bf16(a[m], bb[n], acc[m][n], 0, 0, 0);
        __syncthreads();
    }

    const int col = lane & 15, rb = (lane >> 4) * 4;
#pragma unroll
    for (int m = 0; m < 4; ++m)
#pragma unroll
        for (int n = 0; n < 4; ++n)
#pragma unroll
            for (int j = 0; j < 4; ++j) {
                const int gm = m0 + wm + m * 16 + rb + j;
                const int gn = n0 + wn + n * 16 + col;
                Pz[(size_t)gm * ldc + gn] = acc[m][n][j];
            }
}

// ---------------------------------------------------------------------------
// Split-K reduce + bias + residual -> out_enc (f32). Deterministic fixed-order.
// ---------------------------------------------------------------------------
__global__ __launch_bounds__(256) void reduce_out(
    const float* __restrict__ p0, const float* __restrict__ p1,
    const float* __restrict__ bias, const float* __restrict__ res,
    float* __restrict__ out, int n4)
{
    int i = blockIdx.x * 256 + threadIdx.x;
    const int stride = gridDim.x * 256;
    for (; i < n4; i += stride) {
        const float4 a = ((const float4*)p0)[i];
        const float4 b = ((const float4*)p1)[i];
        const float4 bi = ((const float4*)bias)[i & 255];   // 1024 cols / 4
        const float4 r = ((const float4*)res)[i];
        float4 o;
        o.x = a.x + b.x + bi.x + r.x;
        o.y = a.y + b.y + bi.y + r.y;
        o.z = a.z + b.z + bi.z + r.z;
        o.w = a.w + b.w + bi.w + r.w;
        ((float4*)out)[i] = o;
    }
}

// ---------------------------------------------------------------------------
// Fused attention v4 (R13, unchanged): QBLK=64, grid 1024 = 4 blocks/CU.
// No-max softmax via exp2. Plain __syncthreads.
// ---------------------------------------------------------------------------
__global__ __launch_bounds__(256) void fused_attn(
    const unsigned short* __restrict__ Qb,
    const unsigned short* __restrict__ Kb,
    const unsigned short* __restrict__ Vt,
    float* __restrict__ attn,
    unsigned short* __restrict__ ctx)
{
    __shared__ __align__(16) unsigned short KVs[128][72];  // p1: K128 | p2: K64+V64
    __shared__ __align__(16) unsigned short Ps[64][72];

    const int z = blockIdx.y, b = z >> 4, h = z & 15;
    const int qt = blockIdx.x;                 // 32 tiles of 64 q-rows
    const int t = threadIdx.x, w = t >> 6, lane = t & 63;
    const int l16 = lane & 15, lhi = lane >> 4;

    const unsigned short* Qp = Qb + (size_t)b * kS * kD + (size_t)h * kDK;
    const unsigned short* Kp = Kb + (size_t)b * kS * kD + (size_t)h * kDK;
    const unsigned short* Vp = Vt + (size_t)(b * kD + h * kDV) * kS;
    float* Ap = attn + (size_t)z * kS * kS;

    // ---- Q fragments in registers, pre-scaled by 0.125*log2(e) ----
    bf16x8 q[2];
    const int qrow0 = qt * 64 + w * 16;
#pragma unroll
    for (int kq = 0; kq < 2; ++kq) {
        bf16x8 v = *(const bf16x8*)(Qp + (size_t)(qrow0 + l16) * kD + kq * 32 + lhi * 8);
#pragma unroll
        for (int e = 0; e < 8; ++e)
            v[e] = (short)f2bf(bf2f((unsigned short)v[e]) * 0.18033688011112042f);
        q[kq] = v;
    }

    float lrow[4] = {0.f, 0.f, 0.f, 0.f};

    // ====== pass 1: row sums, 128 keys per LDS stage (16 iters) ======
    for (int kt = 0; kt < 16; ++kt) {
#pragma unroll
        for (int i = 0; i < 4; ++i) {
            const int r = i * 32 + (t >> 3), c = (t & 7) * 8;
            *(bf16x8*)&KVs[r][c] = *(const bf16x8*)(Kp + (size_t)(kt * 128 + r) * kD + c);
        }
        __syncthreads();

        f32x4 s[8];
#pragma unroll
        for (int n = 0; n < 8; ++n) s[n] = (f32x4){0.f, 0.f, 0.f, 0.f};
#pragma unroll
        for (int kq = 0; kq < 2; ++kq)
#pragma unroll
            for (int n = 0; n < 8; ++n) {
                const bf16x8 kf = *(const bf16x8*)&KVs[n * 16 + l16][kq * 32 + lhi * 8];
                s[n] = __builtin_amdgcn_mfma_f32_16x16x32_bf16(q[kq], kf, s[n], 0, 0, 0);
            }

#pragma unroll
        for (int j = 0; j < 4; ++j) {
            float sum = ((fast_exp2(s[0][j]) + fast_exp2(s[1][j]))
                       + (fast_exp2(s[2][j]) + fast_exp2(s[3][j])))
                      + ((fast_exp2(s[4][j]) + fast_exp2(s[5][j]))
                       + (fast_exp2(s[6][j]) + fast_exp2(s[7][j])));
#pragma unroll
            for (int off = 1; off < 16; off <<= 1) sum += __shfl_xor(sum, off);
            lrow[j] += sum;
        }
        __syncthreads();
    }

    float invl[4];
#pragma unroll
    for (int j = 0; j < 4; ++j) invl[j] = 1.0f / lrow[j];

    // ====== pass 2: P = exp2(s)/l, write attn, O += P*V (KVBLK=64) ======
    f32x4 o[4];
#pragma unroll
    for (int n = 0; n < 4; ++n) o[n] = (f32x4){0.f, 0.f, 0.f, 0.f};

    for (int kt = 0; kt < 32; ++kt) {
#pragma unroll
        for (int i = 0; i < 2; ++i) {
            const int r = i * 32 + (t >> 3), c = (t & 7) * 8;
            *(bf16x8*)&KVs[r][c]      = *(const bf16x8*)(Kp + (size_t)(kt * 64 + r) * kD + c);
            *(bf16x8*)&KVs[64 + r][c] = *(const bf16x8*)(Vp + (size_t)r * kS + kt * 64 + c);
        }
        __syncthreads();

        f32x4 s[4];
#pragma unroll
        for (int n = 0; n < 4; ++n) s[n] = (f32x4){0.f, 0.f, 0.f, 0.f};
#pragma unroll
        for (int kq = 0; kq < 2; ++kq)
#pragma unroll
            for (int n = 0; n < 4; ++n) {
                const bf16x8 kf = *(const bf16x8*)&KVs[n * 16 + l16][kq * 32 + lhi * 8];
                s[n] = __builtin_amdgcn_mfma_f32_16x16x32_bf16(q[kq], kf, s[n], 0, 0, 0);
            }

        // P = exp2(s) * invl -> Ps (bf16)
#pragma unroll
        for (int j = 0; j < 4; ++j) {
            const int qrow_l = w * 16 + lhi * 4 + j;
#pragma unroll
            for (int n = 0; n < 4; ++n) {
                const float p = fast_exp2(s[n][j]) * invl[j];
                Ps[qrow_l][n * 16 + l16] = f2bf(p);
            }
        }
        __syncthreads();   // Ps visible before PV reads + attn writeback

        // attn writeback: contiguous nontemporal f32x4 streams (64 rows)
#pragma unroll
        for (int rg = 0; rg < 2; ++rg) {
            const int row = rg * 32 + (t >> 3);
            const int cb  = (t & 7) * 8;
            const bf16x8 pv = *(const bf16x8*)&Ps[row][cb];
            f32x4 f0, f1;
            f0.x = bf2f((unsigned short)pv[0]); f0.y = bf2f((unsigned short)pv[1]);
            f0.z = bf2f((unsigned short)pv[2]); f0.w = bf2f((unsigned short)pv[3]);
            f1.x = bf2f((unsigned short)pv[4]); f1.y = bf2f((unsigned short)pv[5]);
            f1.z = bf2f((unsigned short)pv[6]); f1.w = bf2f((unsigned short)pv[7]);
            float* dst = Ap + (size_t)(qt * 64 + row) * kS + kt * 64 + cb;
            __builtin_nontemporal_store(f0, (f32x4*)dst);
            __builtin_nontemporal_store(f1, (f32x4*)(dst + 4));
        }

#pragma unroll
        for (int ks = 0; ks < 2; ++ks) {
            const bf16x8 pa = *(const bf16x8*)&Ps[w * 16 + l16][ks * 32 + lhi * 8];
#pragma unroll
            for (int n = 0; n < 4; ++n) {
                const bf16x8 vf = *(const bf16x8*)&KVs[64 + n * 16 + l16][ks * 32 + lhi * 8];
                o[n] = __builtin_amdgcn_mfma_f32_16x16x32_bf16(pa, vf, o[n], 0, 0, 0);
            }
        }
        __syncthreads();   // all reads done before next tile overwrites
    }

    // ---- ctx write: [B,S,H*DV] bf16 ----
#pragma unroll
    for (int n = 0; n < 4; ++n)
#pragma unroll
        for (int j = 0; j < 4; ++j) {
            const int qg = qt * 64 + w * 16 + lhi * 4 + j;
            const int dv = n * 16 + l16;
            ctx[((size_t)b * kS + qg) * kD + h * kDV + dv] = f2bf(o[n][j]);
        }
}

// ---------------------------------------------------------------------------
extern "C" void kernel_launch(void* const* d_in, const int* in_sizes, int n_in,
                              void* d_out, int out_size, void* d_ws, size_t ws_size,
                              hipStream_t stream) {
    (void)in_sizes; (void)n_in; (void)out_size; (void)ws_size;

    const float* x      = (const float*)d_in[0];
    const float* w_qs   = (const float*)d_in[1];
    const float* w_ks   = (const float*)d_in[2];
    const float* w_vs   = (const float*)d_in[3];
    const float* fc_w   = (const float*)d_in[4];
    const float* fc_b   = (const float*)d_in[5];
    const float* ln1_g  = (const float*)d_in[6];
    const float* ln1_b  = (const float*)d_in[7];
    const float* ffn_w1 = (const float*)d_in[8];
    const float* ffn_b1 = (const float*)d_in[9];
    const float* ffn_w2 = (const float*)d_in[10];
    const float* ffn_b2 = (const float*)d_in[11];
    const float* ln2_g  = (const float*)d_in[12];
    const float* ln2_b  = (const float*)d_in[13];

    float* out_enc  = (float*)d_out;                   // [B,S,D] f32
    float* out_attn = out_enc + (size_t)kM * kD;       // [B,H,S,S] f32

    // Workspace (128 MB)
    unsigned short* xb   = (unsigned short*)d_ws;      // x bf16
    unsigned short* qinb = xb   + (size_t)4194304;     // LN1(x)
    unsigned short* Qb   = qinb + (size_t)4194304;     // Q
    unsigned short* Kb   = Qb   + (size_t)4194304;     // K
    unsigned short* Vt   = Kb   + (size_t)4194304;     // V^T
    unsigned short* ctxb = Vt   + (size_t)4194304;     // ctx
    unsigned short* hb   = ctxb + (size_t)4194304;     // LN2(attn_out)
    unsigned short* gb   = hb   + (size_t)4194304;     // gelu out
    unsigned short* wqsb = gb   + (size_t)16777216;    // weights bf16 (contig 12M)
    unsigned short* wksb = wqsb + (size_t)1048576;
    unsigned short* wvsb = wksb + (size_t)1048576;
    unsigned short* fcwb = wvsb + (size_t)1048576;
    unsigned short* w1b  = fcwb + (size_t)1048576;
    unsigned short* w2b  = w1b  + (size_t)4194304;
    float* attn_out      = (float*)(w2b + (size_t)4194304);  // f32 16MB

    // Split-K partials reuse xb..Kb (dead by FFN2 time): 2 x 16 MB f32
    float* part0 = (float*)xb;
    float* part1 = (float*)Qb;

    const dim3 blk(256);

    // ---- all weight converts in one dispatch ----
    cvt_weights<<<2048, blk, 0, stream>>>(w_qs, w_ks, w_vs, fc_w, ffn_w1, ffn_w2, wqsb);

    // ---- LN1 (wave-per-row; also emits x as bf16) ----
    ln_bf16_kernel<true><<<kM / 4, blk, 0, stream>>>(x, ln1_g, ln1_b, qinb, xb);

    // ---- fused Q/K/V projections ----
    qkv_gemm<<<dim3(24, 32), blk, 0, stream>>>(qinb, xb, wqsb, wksb, wvsb, Qb, Kb, Vt);

    // ---- fused scores+softmax+PV (QBLK=64, 1024 blocks = 4/CU) ----
    fused_attn<<<dim3(32, 32), blk, 0, stream>>>(Qb, Kb, Vt, out_attn, ctxb);

    // ---- attn_out = ctx @ fc_w^T + fc_b + x (f32): R13 config ----
    gemm_mfma<128, 64, false, true, true, false><<<dim3(16, 32), blk, 0, stream>>>(
        ctxb, kD, fcwb, kD, attn_out, kD, fc_b, x, kD, kD);

    // ---- LN2 (wave-per-row) ----
    ln_bf16_kernel<false><<<kM / 4, blk, 0, stream>>>(attn_out, ln2_g, ln2_b, hb, nullptr);

    // ---- g = gelu(h @ ffn_w1^T + b1) -> bf16 (128^2, 1024 blocks) ----
    gemm_mfma<128, 128, true, true, false, true><<<dim3(32, 32), blk, 0, stream>>>(
        hb, kD, w1b, kD, gb, kDFF, ffn_b1, nullptr, 0, kD);

    // ---- FFN2 split-K=2 (R13): partials then reduce(+bias+residual) ----
    gemm_splitk<<<dim3(8, 32, 2), blk, 0, stream>>>(
        gb, kDFF, w2b, kDFF, part0, kD, kDFF, 2);
    reduce_out<<<2048, blk, 0, stream>>>(part0, part1, ffn_b2, attn_out,
                                         out_enc, kM * kD / 4);
}